// Round 18
// baseline (275.630 us; speedup 1.0000x reference)
//
#include <hip/hip_runtime.h>
#include <hip/hip_bf16.h>

#define B_ 8
#define C_ 128
#define N_ 4096   // H*W = 64*64

typedef float  f32x4  __attribute__((ext_vector_type(4)));

__device__ __forceinline__ float fp8tof(unsigned u, int sel) {
    switch (sel & 3) {
        case 0:  return __builtin_amdgcn_cvt_f32_fp8(u, 0);
        case 1:  return __builtin_amdgcn_cvt_f32_fp8(u, 1);
        case 2:  return __builtin_amdgcn_cvt_f32_fp8(u, 2);
        default: return __builtin_amdgcn_cvt_f32_fp8(u, 3);
    }
}

// ---------------------------------------------------------------------------
// K1: channel softmax over C for each (b, n). EXACT R14/R16 version.
// ---------------------------------------------------------------------------
__global__ __launch_bounds__(128) void chan_softmax(const float* __restrict__ x,
                                                    float* __restrict__ xs,
                                                    unsigned char* __restrict__ vT8,
                                                    float* __restrict__ S)
{
    int idx = blockIdx.x * 128 + threadIdx.x;     // (b, n) flattened, 32768 total
    if (idx < B_ * C_) S[idx] = 0.0f;

    int b = idx >> 12;
    int n = idx & (N_ - 1);

    const float* xp = x + (size_t)b * C_ * N_ + n;

    float xv[C_];
    #pragma unroll
    for (int c = 0; c < C_; ++c) xv[c] = xp[(size_t)c * N_];   // independent loads

    float m = xv[0];
    #pragma unroll
    for (int c = 1; c < C_; ++c) m = fmaxf(m, xv[c]);

    float s = 0.f;
    #pragma unroll
    for (int c = 0; c < C_; ++c) { xv[c] = __expf(xv[c] - m); s += xv[c]; }
    float inv = 1.f / s;

    float* op = xs + (size_t)b * C_ * N_ + n;
    uint4* vp = reinterpret_cast<uint4*>(vT8 + ((size_t)b * N_ + n) * C_);

    #pragma unroll
    for (int c0 = 0; c0 < C_; c0 += 16) {
        unsigned pk[4];
        #pragma unroll
        for (int wi = 0; wi < 4; ++wi) {
            float v0 = xv[c0 + wi * 4 + 0] * inv;
            float v1 = xv[c0 + wi * 4 + 1] * inv;
            float v2 = xv[c0 + wi * 4 + 2] * inv;
            float v3 = xv[c0 + wi * 4 + 3] * inv;
            op[(size_t)(c0 + wi * 4 + 0) * N_] = v0;
            op[(size_t)(c0 + wi * 4 + 1) * N_] = v1;
            op[(size_t)(c0 + wi * 4 + 2) * N_] = v2;
            op[(size_t)(c0 + wi * 4 + 3) * N_] = v3;
            unsigned u = __builtin_amdgcn_cvt_pk_fp8_f32(v0, v1, 0, false);
            u = __builtin_amdgcn_cvt_pk_fp8_f32(v2, v3, u, true);
            pk[wi] = u;
        }
        uint4 q; q.x = pk[0]; q.y = pk[1]; q.z = pk[2]; q.w = pk[3];
        vp[c0 >> 4] = q;   // 16 B store, row-contiguous
    }
}

// ---------------------------------------------------------------------------
// K2: S[b][c] += partial column sums of vT (fp8 decode). EXACT R13-R16 version.
// ---------------------------------------------------------------------------
__global__ __launch_bounds__(256) void colsum(const unsigned char* __restrict__ vT8,
                                              float* __restrict__ S)
{
    int bid   = blockIdx.x;
    int b     = bid & 7;
    int chunk = bid >> 3;                 // 0..31 (128 rows each)
    int t     = threadIdx.x;
    int g     = t & 31;
    int sub   = t >> 5;                   // 0..7 (16 rows each)

    const unsigned* base = reinterpret_cast<const unsigned*>(vT8 + (size_t)b * N_ * C_)
                         + (size_t)(chunk * 128 + sub * 16) * (C_ / 4) + g;

    float a0 = 0.f, a1 = 0.f, a2 = 0.f, a3 = 0.f;
    #pragma unroll 4
    for (int r = 0; r < 16; ++r) {
        unsigned u = base[(size_t)r * (C_ / 4)];  // 4 fp8
        a0 += __builtin_amdgcn_cvt_f32_fp8(u, 0);
        a1 += __builtin_amdgcn_cvt_f32_fp8(u, 1);
        a2 += __builtin_amdgcn_cvt_f32_fp8(u, 2);
        a3 += __builtin_amdgcn_cvt_f32_fp8(u, 3);
    }

    __shared__ float st[8][C_];
    st[sub][g * 4 + 0] = a0;
    st[sub][g * 4 + 1] = a1;
    st[sub][g * 4 + 2] = a2;
    st[sub][g * 4 + 3] = a3;
    __syncthreads();
    if (t < C_) {
        float s = 0.f;
        #pragma unroll
        for (int k = 0; k < 8; ++k) s += st[k][t];
        atomicAdd(&S[b * C_ + t], s);
    }
}

// ---------------------------------------------------------------------------
// K3: attention[b][i][j] = exp(<v_i,v_j>) * inv_i, single pass.
// R16 per-jt schedule EXACTLY (stage -> sync -> full-row 1 KB NT stores ->
// sync); ONE change: 32-row blocks (1024 blocks) so LDS = 33.4 KB ->
// 4 blocks/CU (16 waves/CU, 2x TLP) to cover store-queue parking. a8/acc
// halve (est ~110 VGPR, fits LB(256,4)). B-panel rereads double but are
// L2-resident fp8 (0.5 MB/batch).
// ---------------------------------------------------------------------------
__global__ __launch_bounds__(256, 4) void att_write(const unsigned char* __restrict__ vT8,
                                                    const float* __restrict__ S,
                                                    float* __restrict__ att)
{
    __shared__ float tile[32][260];       // block-shared 32 x 256 staging (+pad)
    __shared__ float inv_lds[32];

    int bid = blockIdx.x;
    int b = bid & 7;                       // batch pinned to XCD
    int rowblock = bid >> 3;               // 0..127
    int rowbase = rowblock * 32;
    int rot = rowblock & 15;               // jt phase rotation (kept from R14)

    int w    = threadIdx.x >> 6;           // wave id: column window within tile
    int lane = threadIdx.x & 63;
    int r16  = lane & 15;
    int kg   = lane >> 4;

    const unsigned char* base = vT8 + (size_t)b * N_ * C_;

    // A fragments: rows rowbase..rowbase+31, full K=128. 8 x long = 16 VGPR.
    long a8[2][4];
    #pragma unroll
    for (int mi = 0; mi < 2; ++mi)
        #pragma unroll
        for (int ks = 0; ks < 4; ++ks)
            a8[mi][ks] = *reinterpret_cast<const long*>(
                base + (size_t)(rowbase + mi * 16 + r16) * C_ + ks * 32 + kg * 8);

    // inv_i = 1/(N + v_i.S): first-order denominator (validated R4+).
    const float* Sb = S + b * C_;
    #pragma unroll
    for (int mi = 0; mi < 2; ++mi) {
        float d = 0.f;
        #pragma unroll
        for (int ks = 0; ks < 4; ++ks) {
            int k0 = ks * 32 + kg * 8;
            unsigned lo = (unsigned)(a8[mi][ks] & 0xffffffffu);
            unsigned hi = (unsigned)(((unsigned long)a8[mi][ks]) >> 32);
            #pragma unroll
            for (int j = 0; j < 4; ++j) d += fp8tof(lo, j) * Sb[k0 + j];
            #pragma unroll
            for (int j = 0; j < 4; ++j) d += fp8tof(hi, j) * Sb[k0 + 4 + j];
        }
        d += __shfl_xor(d, 16, 64);
        d += __shfl_xor(d, 32, 64);
        if (threadIdx.x < 16) inv_lds[mi * 16 + r16] = 1.0f / ((float)N_ + d);
    }
    __syncthreads();

    // per-wave iv for its 8 store rows (w*8 .. w*8+7), row-uniform values
    float iv_reg[8];
    #pragma unroll
    for (int p = 0; p < 8; ++p) iv_reg[p] = inv_lds[w * 8 + p];

    float* ab = att + (size_t)b * N_ * N_;

    // prologue: B-frags for first (rotated) tile
    long bb8[4][4];
    #pragma unroll
    for (int ks = 0; ks < 4; ++ks)
        #pragma unroll
        for (int nj = 0; nj < 4; ++nj)
            bb8[ks][nj] = *reinterpret_cast<const long*>(
                base + (size_t)(rot * 256 + w * 64 + nj * 16 + r16) * C_ + ks * 32 + kg * 8);

    #pragma unroll 1
    for (int jt0 = 0; jt0 < 16; ++jt0) {
        int jt = (jt0 + rot) & 15;

        f32x4 acc[2][4] = {};
        #pragma unroll
        for (int ks = 0; ks < 4; ++ks)
            #pragma unroll
            for (int mi = 0; mi < 2; ++mi)
                #pragma unroll
                for (int nj = 0; nj < 4; ++nj)
                    acc[mi][nj] = __builtin_amdgcn_mfma_f32_16x16x32_fp8_fp8(
                        a8[mi][ks], bb8[ks][nj], acc[mi][nj], 0, 0, 0);

        // prefetch next tile's B-frags (WAR reuse) BEFORE the stores.
        if (jt0 < 15) {
            int pf = (((jt0 + 1 + rot) & 15) * 256) + w * 64;
            #pragma unroll
            for (int ks = 0; ks < 4; ++ks)
                #pragma unroll
                for (int nj = 0; nj < 4; ++nj)
                    bb8[ks][nj] = *reinterpret_cast<const long*>(
                        base + (size_t)(pf + nj * 16 + r16) * C_ + ks * 32 + kg * 8);
        }

        // stage this wave's quadrant into the BLOCK tile:
        // row = mi*16+kg*4+r, col = w*64 + nj*16 + r16
        #pragma unroll
        for (int mi = 0; mi < 2; ++mi)
            #pragma unroll
            for (int nj = 0; nj < 4; ++nj)
                #pragma unroll
                for (int r = 0; r < 4; ++r)
                    tile[mi * 16 + kg * 4 + r][w * 64 + nj * 16 + r16] = acc[mi][nj][r];

        __syncthreads();

        // store phase: wave w owns rows w*8..w*8+7; one instruction per row
        // = 64 lanes x 16 B = 1 KB fully contiguous. NONTEMPORAL (R17: NT is
        // +23 us — L2 churn protection is essential).
        #pragma unroll
        for (int p = 0; p < 8; ++p) {
            int row = w * 8 + p;
            f32x4 o = *reinterpret_cast<const f32x4*>(&tile[row][lane * 4]);
            float iv = iv_reg[p];
            #pragma unroll
            for (int i = 0; i < 4; ++i) o[i] = __expf(o[i]) * iv;
            __builtin_nontemporal_store(o,
                reinterpret_cast<f32x4*>(&ab[(size_t)(rowbase + row) * N_ + jt * 256 + lane * 4]));
        }

        __syncthreads();   // tile reusable next jt
    }
}

// ---------------------------------------------------------------------------
// K4: out = gamma * (V @ attention^T) + xs. EXACT R13-R16 version.
// ---------------------------------------------------------------------------
__global__ __launch_bounds__(256) void pv_update(const float* __restrict__ gamma,
                                                 const unsigned char* __restrict__ vT8,
                                                 const float* __restrict__ att,
                                                 float* __restrict__ out)
{
    float g = gamma[0];
    if (g == 0.0f) return;

    int b  = blockIdx.y;
    int n0 = blockIdx.x * 128 + (threadIdx.x >> 7) * 64;
    int c  = threadIdx.x & 127;

    const unsigned char* vb = vT8 + (size_t)b * N_ * C_;

    for (int i = 0; i < 64; ++i) {
        int n = n0 + i;
        const float* arow = att + ((size_t)b * N_ + n) * N_;
        float acc = 0.f;
        for (int m = 0; m < N_; ++m)
            acc += __builtin_amdgcn_cvt_f32_fp8((unsigned)vb[(size_t)m * C_ + c], 0) * arow[m];
        size_t oi = ((size_t)b * C_ + c) * N_ + n;
        out[oi] = g * acc + out[oi];
    }
}

// ---------------------------------------------------------------------------
extern "C" void kernel_launch(void* const* d_in, const int* in_sizes, int n_in,
                              void* d_out, int out_size, void* d_ws, size_t ws_size,
                              hipStream_t stream)
{
    const float* x     = (const float*)d_in[0];
    const float* gamma = (const float*)d_in[1];

    float* out = (float*)d_out;                        // [B][C][N]  (4,194,304 f32)
    float* att = out + (size_t)B_ * C_ * N_;           // [B][N][N]  (134,217,728 f32)
    unsigned char* vT8 = (unsigned char*)d_ws;         // [B][N][C]  fp8, 4 MB
    float* S   = (float*)(vT8 + (size_t)B_ * N_ * C_); // [B][C] f32, 4 KB

    chan_softmax<<<256, 128, 0, stream>>>(x, out, vT8, S);
    colsum<<<256, 256, 0, stream>>>(vT8, S);
    att_write<<<(N_ / 32) * B_, 256, 0, stream>>>(vT8, S, att);
    pv_update<<<dim3(32, B_), 256, 0, stream>>>(gamma, vT8, att, out);
}

// Round 19
// 122.948 us; speedup vs baseline: 2.2418x; 2.2418x over previous
//
#include <hip/hip_runtime.h>
#include <hip/hip_bf16.h>

#define B_ 8
#define C_ 128
#define N_ 4096   // H*W = 64*64

typedef float  f32x4  __attribute__((ext_vector_type(4)));

__device__ __forceinline__ float fp8tof(unsigned u, int sel) {
    switch (sel & 3) {
        case 0:  return __builtin_amdgcn_cvt_f32_fp8(u, 0);
        case 1:  return __builtin_amdgcn_cvt_f32_fp8(u, 1);
        case 2:  return __builtin_amdgcn_cvt_f32_fp8(u, 2);
        default: return __builtin_amdgcn_cvt_f32_fp8(u, 3);
    }
}

// ---------------------------------------------------------------------------
// K1: channel softmax over C for each (b, n). EXACT R14/R16 version.
// ---------------------------------------------------------------------------
__global__ __launch_bounds__(128) void chan_softmax(const float* __restrict__ x,
                                                    float* __restrict__ xs,
                                                    unsigned char* __restrict__ vT8,
                                                    float* __restrict__ S)
{
    int idx = blockIdx.x * 128 + threadIdx.x;     // (b, n) flattened, 32768 total
    if (idx < B_ * C_) S[idx] = 0.0f;

    int b = idx >> 12;
    int n = idx & (N_ - 1);

    const float* xp = x + (size_t)b * C_ * N_ + n;

    float xv[C_];
    #pragma unroll
    for (int c = 0; c < C_; ++c) xv[c] = xp[(size_t)c * N_];   // independent loads

    float m = xv[0];
    #pragma unroll
    for (int c = 1; c < C_; ++c) m = fmaxf(m, xv[c]);

    float s = 0.f;
    #pragma unroll
    for (int c = 0; c < C_; ++c) { xv[c] = __expf(xv[c] - m); s += xv[c]; }
    float inv = 1.f / s;

    float* op = xs + (size_t)b * C_ * N_ + n;
    uint4* vp = reinterpret_cast<uint4*>(vT8 + ((size_t)b * N_ + n) * C_);

    #pragma unroll
    for (int c0 = 0; c0 < C_; c0 += 16) {
        unsigned pk[4];
        #pragma unroll
        for (int wi = 0; wi < 4; ++wi) {
            float v0 = xv[c0 + wi * 4 + 0] * inv;
            float v1 = xv[c0 + wi * 4 + 1] * inv;
            float v2 = xv[c0 + wi * 4 + 2] * inv;
            float v3 = xv[c0 + wi * 4 + 3] * inv;
            op[(size_t)(c0 + wi * 4 + 0) * N_] = v0;
            op[(size_t)(c0 + wi * 4 + 1) * N_] = v1;
            op[(size_t)(c0 + wi * 4 + 2) * N_] = v2;
            op[(size_t)(c0 + wi * 4 + 3) * N_] = v3;
            unsigned u = __builtin_amdgcn_cvt_pk_fp8_f32(v0, v1, 0, false);
            u = __builtin_amdgcn_cvt_pk_fp8_f32(v2, v3, u, true);
            pk[wi] = u;
        }
        uint4 q; q.x = pk[0]; q.y = pk[1]; q.z = pk[2]; q.w = pk[3];
        vp[c0 >> 4] = q;   // 16 B store, row-contiguous
    }
}

// ---------------------------------------------------------------------------
// K2: S[b][c] += partial column sums of vT (fp8 decode). EXACT R13-R16 version.
// ---------------------------------------------------------------------------
__global__ __launch_bounds__(256) void colsum(const unsigned char* __restrict__ vT8,
                                              float* __restrict__ S)
{
    int bid   = blockIdx.x;
    int b     = bid & 7;
    int chunk = bid >> 3;                 // 0..31 (128 rows each)
    int t     = threadIdx.x;
    int g     = t & 31;
    int sub   = t >> 5;                   // 0..7 (16 rows each)

    const unsigned* base = reinterpret_cast<const unsigned*>(vT8 + (size_t)b * N_ * C_)
                         + (size_t)(chunk * 128 + sub * 16) * (C_ / 4) + g;

    float a0 = 0.f, a1 = 0.f, a2 = 0.f, a3 = 0.f;
    #pragma unroll 4
    for (int r = 0; r < 16; ++r) {
        unsigned u = base[(size_t)r * (C_ / 4)];  // 4 fp8
        a0 += __builtin_amdgcn_cvt_f32_fp8(u, 0);
        a1 += __builtin_amdgcn_cvt_f32_fp8(u, 1);
        a2 += __builtin_amdgcn_cvt_f32_fp8(u, 2);
        a3 += __builtin_amdgcn_cvt_f32_fp8(u, 3);
    }

    __shared__ float st[8][C_];
    st[sub][g * 4 + 0] = a0;
    st[sub][g * 4 + 1] = a1;
    st[sub][g * 4 + 2] = a2;
    st[sub][g * 4 + 3] = a3;
    __syncthreads();
    if (t < C_) {
        float s = 0.f;
        #pragma unroll
        for (int k = 0; k < 8; ++k) s += st[k][t];
        atomicAdd(&S[b * C_ + t], s);
    }
}

// ---------------------------------------------------------------------------
// K3: attention[b][i][j] = exp(<v_i,v_j>) * inv_i, single pass.
// EXACT R16 geometry (64-row blocks, LB(256,2), block-shared [64][260] tile,
// full-row 1 KB NT stores). ONE change: exp(acc)*iv is computed BEFORE LDS
// staging (from registers, overlapping MFMA/prefetch), so the store phase is
// a pure ds_read -> NT-store chain (no transcendental on the critical path).
// ---------------------------------------------------------------------------
__global__ __launch_bounds__(256, 2) void att_write(const unsigned char* __restrict__ vT8,
                                                    const float* __restrict__ S,
                                                    float* __restrict__ att)
{
    __shared__ float tile[64][260];       // block-shared 64 x 256 staging (+pad)
    __shared__ float inv_lds[64];

    int bid = blockIdx.x;
    int b = bid & 7;                       // batch pinned to XCD
    int rowblock = bid >> 3;
    int rowbase = rowblock * 64;
    int rot = rowblock & 15;               // jt phase rotation (kept from R14)

    int w    = threadIdx.x >> 6;           // wave id: column window within tile
    int lane = threadIdx.x & 63;
    int r16  = lane & 15;
    int kg   = lane >> 4;

    const unsigned char* base = vT8 + (size_t)b * N_ * C_;

    // A fragments: rows rowbase..rowbase+63, full K=128. 16 x long = 32 VGPR.
    long a8[4][4];
    #pragma unroll
    for (int mi = 0; mi < 4; ++mi)
        #pragma unroll
        for (int ks = 0; ks < 4; ++ks)
            a8[mi][ks] = *reinterpret_cast<const long*>(
                base + (size_t)(rowbase + mi * 16 + r16) * C_ + ks * 32 + kg * 8);

    // inv_i = 1/(N + v_i.S): first-order denominator (validated R4+).
    const float* Sb = S + b * C_;
    #pragma unroll
    for (int mi = 0; mi < 4; ++mi) {
        float d = 0.f;
        #pragma unroll
        for (int ks = 0; ks < 4; ++ks) {
            int k0 = ks * 32 + kg * 8;
            unsigned lo = (unsigned)(a8[mi][ks] & 0xffffffffu);
            unsigned hi = (unsigned)(((unsigned long)a8[mi][ks]) >> 32);
            #pragma unroll
            for (int j = 0; j < 4; ++j) d += fp8tof(lo, j) * Sb[k0 + j];
            #pragma unroll
            for (int j = 0; j < 4; ++j) d += fp8tof(hi, j) * Sb[k0 + 4 + j];
        }
        d += __shfl_xor(d, 16, 64);
        d += __shfl_xor(d, 32, 64);
        if (threadIdx.x < 16) inv_lds[mi * 16 + r16] = 1.0f / ((float)N_ + d);
    }
    __syncthreads();

    // per-thread iv for the acc elements it stages: row = mi*16 + kg*4 + r
    float iv_acc[4][4];
    #pragma unroll
    for (int mi = 0; mi < 4; ++mi)
        #pragma unroll
        for (int r = 0; r < 4; ++r)
            iv_acc[mi][r] = inv_lds[mi * 16 + kg * 4 + r];

    float* ab = att + (size_t)b * N_ * N_;

    // prologue: B-frags for first (rotated) tile
    long bb8[4][4];
    #pragma unroll
    for (int ks = 0; ks < 4; ++ks)
        #pragma unroll
        for (int nj = 0; nj < 4; ++nj)
            bb8[ks][nj] = *reinterpret_cast<const long*>(
                base + (size_t)(rot * 256 + w * 64 + nj * 16 + r16) * C_ + ks * 32 + kg * 8);

    #pragma unroll 1
    for (int jt0 = 0; jt0 < 16; ++jt0) {
        int jt = (jt0 + rot) & 15;

        f32x4 acc[4][4] = {};
        #pragma unroll
        for (int ks = 0; ks < 4; ++ks)
            #pragma unroll
            for (int mi = 0; mi < 4; ++mi)
                #pragma unroll
                for (int nj = 0; nj < 4; ++nj)
                    acc[mi][nj] = __builtin_amdgcn_mfma_f32_16x16x32_fp8_fp8(
                        a8[mi][ks], bb8[ks][nj], acc[mi][nj], 0, 0, 0);

        // prefetch next tile's B-frags (WAR reuse) BEFORE the stores.
        if (jt0 < 15) {
            int pf = (((jt0 + 1 + rot) & 15) * 256) + w * 64;
            #pragma unroll
            for (int ks = 0; ks < 4; ++ks)
                #pragma unroll
                for (int nj = 0; nj < 4; ++nj)
                    bb8[ks][nj] = *reinterpret_cast<const long*>(
                        base + (size_t)(pf + nj * 16 + r16) * C_ + ks * 32 + kg * 8);
        }

        // finish softmax IN REGISTERS (exp overlaps prefetch latency), then
        // stage FINAL values into the block tile.
        #pragma unroll
        for (int mi = 0; mi < 4; ++mi)
            #pragma unroll
            for (int nj = 0; nj < 4; ++nj)
                #pragma unroll
                for (int r = 0; r < 4; ++r)
                    tile[mi * 16 + kg * 4 + r][w * 64 + nj * 16 + r16] =
                        __expf(acc[mi][nj][r]) * iv_acc[mi][r];

        __syncthreads();

        // store phase: wave w owns rows w*16..w*16+15; one instruction per row
        // = 64 lanes x 16 B = 1 KB fully contiguous. Pure ds_read -> NT store.
        #pragma unroll
        for (int p = 0; p < 16; ++p) {
            int row = w * 16 + p;
            f32x4 o = *reinterpret_cast<const f32x4*>(&tile[row][lane * 4]);
            __builtin_nontemporal_store(o,
                reinterpret_cast<f32x4*>(&ab[(size_t)(rowbase + row) * N_ + jt * 256 + lane * 4]));
        }

        __syncthreads();   // tile reusable next jt
    }
}

// ---------------------------------------------------------------------------
// K4: out = gamma * (V @ attention^T) + xs. EXACT R13-R16 version.
// ---------------------------------------------------------------------------
__global__ __launch_bounds__(256) void pv_update(const float* __restrict__ gamma,
                                                 const unsigned char* __restrict__ vT8,
                                                 const float* __restrict__ att,
                                                 float* __restrict__ out)
{
    float g = gamma[0];
    if (g == 0.0f) return;

    int b  = blockIdx.y;
    int n0 = blockIdx.x * 128 + (threadIdx.x >> 7) * 64;
    int c  = threadIdx.x & 127;

    const unsigned char* vb = vT8 + (size_t)b * N_ * C_;

    for (int i = 0; i < 64; ++i) {
        int n = n0 + i;
        const float* arow = att + ((size_t)b * N_ + n) * N_;
        float acc = 0.f;
        for (int m = 0; m < N_; ++m)
            acc += __builtin_amdgcn_cvt_f32_fp8((unsigned)vb[(size_t)m * C_ + c], 0) * arow[m];
        size_t oi = ((size_t)b * C_ + c) * N_ + n;
        out[oi] = g * acc + out[oi];
    }
}

// ---------------------------------------------------------------------------
extern "C" void kernel_launch(void* const* d_in, const int* in_sizes, int n_in,
                              void* d_out, int out_size, void* d_ws, size_t ws_size,
                              hipStream_t stream)
{
    const float* x     = (const float*)d_in[0];
    const float* gamma = (const float*)d_in[1];

    float* out = (float*)d_out;                        // [B][C][N]  (4,194,304 f32)
    float* att = out + (size_t)B_ * C_ * N_;           // [B][N][N]  (134,217,728 f32)
    unsigned char* vT8 = (unsigned char*)d_ws;         // [B][N][C]  fp8, 4 MB
    float* S   = (float*)(vT8 + (size_t)B_ * N_ * C_); // [B][C] f32, 4 KB

    chan_softmax<<<256, 128, 0, stream>>>(x, out, vT8, S);
    colsum<<<256, 256, 0, stream>>>(vT8, S);
    att_write<<<(N_ / 64) * B_, 256, 0, stream>>>(vT8, S, att);
    pv_update<<<dim3(32, B_), 256, 0, stream>>>(gamma, vT8, att, out);
}

// Round 20
// 122.394 us; speedup vs baseline: 2.2520x; 1.0045x over previous
//
#include <hip/hip_runtime.h>
#include <hip/hip_bf16.h>

#define B_ 8
#define C_ 128
#define N_ 4096   // H*W = 64*64

typedef float  f32x4  __attribute__((ext_vector_type(4)));

__device__ __forceinline__ float fp8tof(unsigned u, int sel) {
    switch (sel & 3) {
        case 0:  return __builtin_amdgcn_cvt_f32_fp8(u, 0);
        case 1:  return __builtin_amdgcn_cvt_f32_fp8(u, 1);
        case 2:  return __builtin_amdgcn_cvt_f32_fp8(u, 2);
        default: return __builtin_amdgcn_cvt_f32_fp8(u, 3);
    }
}

// lgkm-only barrier: orders LDS ops across the block WITHOUT the compiler's
// conservative vmcnt(0) drain (which would serialize the NT store stream and
// prefetch loads every jt). HK 8-phase pattern (raw s_barrier + counted vm).
__device__ __forceinline__ void lds_barrier() {
    asm volatile("s_waitcnt lgkmcnt(0)" ::: "memory");
    __builtin_amdgcn_s_barrier();
}

// ---------------------------------------------------------------------------
// K1: channel softmax over C for each (b, n). EXACT R14/R16/R19 version.
// ---------------------------------------------------------------------------
__global__ __launch_bounds__(128) void chan_softmax(const float* __restrict__ x,
                                                    float* __restrict__ xs,
                                                    unsigned char* __restrict__ vT8,
                                                    float* __restrict__ S)
{
    int idx = blockIdx.x * 128 + threadIdx.x;     // (b, n) flattened, 32768 total
    if (idx < B_ * C_) S[idx] = 0.0f;

    int b = idx >> 12;
    int n = idx & (N_ - 1);

    const float* xp = x + (size_t)b * C_ * N_ + n;

    float xv[C_];
    #pragma unroll
    for (int c = 0; c < C_; ++c) xv[c] = xp[(size_t)c * N_];   // independent loads

    float m = xv[0];
    #pragma unroll
    for (int c = 1; c < C_; ++c) m = fmaxf(m, xv[c]);

    float s = 0.f;
    #pragma unroll
    for (int c = 0; c < C_; ++c) { xv[c] = __expf(xv[c] - m); s += xv[c]; }
    float inv = 1.f / s;

    float* op = xs + (size_t)b * C_ * N_ + n;
    uint4* vp = reinterpret_cast<uint4*>(vT8 + ((size_t)b * N_ + n) * C_);

    #pragma unroll
    for (int c0 = 0; c0 < C_; c0 += 16) {
        unsigned pk[4];
        #pragma unroll
        for (int wi = 0; wi < 4; ++wi) {
            float v0 = xv[c0 + wi * 4 + 0] * inv;
            float v1 = xv[c0 + wi * 4 + 1] * inv;
            float v2 = xv[c0 + wi * 4 + 2] * inv;
            float v3 = xv[c0 + wi * 4 + 3] * inv;
            op[(size_t)(c0 + wi * 4 + 0) * N_] = v0;
            op[(size_t)(c0 + wi * 4 + 1) * N_] = v1;
            op[(size_t)(c0 + wi * 4 + 2) * N_] = v2;
            op[(size_t)(c0 + wi * 4 + 3) * N_] = v3;
            unsigned u = __builtin_amdgcn_cvt_pk_fp8_f32(v0, v1, 0, false);
            u = __builtin_amdgcn_cvt_pk_fp8_f32(v2, v3, u, true);
            pk[wi] = u;
        }
        uint4 q; q.x = pk[0]; q.y = pk[1]; q.z = pk[2]; q.w = pk[3];
        vp[c0 >> 4] = q;   // 16 B store, row-contiguous
    }
}

// ---------------------------------------------------------------------------
// K2: S[b][c] += partial column sums of vT (fp8 decode). EXACT R13-R19 version.
// ---------------------------------------------------------------------------
__global__ __launch_bounds__(256) void colsum(const unsigned char* __restrict__ vT8,
                                              float* __restrict__ S)
{
    int bid   = blockIdx.x;
    int b     = bid & 7;
    int chunk = bid >> 3;                 // 0..31 (128 rows each)
    int t     = threadIdx.x;
    int g     = t & 31;
    int sub   = t >> 5;                   // 0..7 (16 rows each)

    const unsigned* base = reinterpret_cast<const unsigned*>(vT8 + (size_t)b * N_ * C_)
                         + (size_t)(chunk * 128 + sub * 16) * (C_ / 4) + g;

    float a0 = 0.f, a1 = 0.f, a2 = 0.f, a3 = 0.f;
    #pragma unroll 4
    for (int r = 0; r < 16; ++r) {
        unsigned u = base[(size_t)r * (C_ / 4)];  // 4 fp8
        a0 += __builtin_amdgcn_cvt_f32_fp8(u, 0);
        a1 += __builtin_amdgcn_cvt_f32_fp8(u, 1);
        a2 += __builtin_amdgcn_cvt_f32_fp8(u, 2);
        a3 += __builtin_amdgcn_cvt_f32_fp8(u, 3);
    }

    __shared__ float st[8][C_];
    st[sub][g * 4 + 0] = a0;
    st[sub][g * 4 + 1] = a1;
    st[sub][g * 4 + 2] = a2;
    st[sub][g * 4 + 3] = a3;
    __syncthreads();
    if (t < C_) {
        float s = 0.f;
        #pragma unroll
        for (int k = 0; k < 8; ++k) s += st[k][t];
        atomicAdd(&S[b * C_ + t], s);
    }
}

// ---------------------------------------------------------------------------
// K3: attention[b][i][j] = exp(<v_i,v_j>) * inv_i, single pass.
// EXACT R19 structure (64-row blocks, LB(256,2), exp-in-registers before
// staging, full-row 1 KB NT stores). ONE change: both __syncthreads replaced
// by lgkm-only barriers, so the per-jt barriers no longer force vmcnt(0)
// drains of the 16 in-flight NT stores + 16 prefetch loads (2x per jt).
// ---------------------------------------------------------------------------
__global__ __launch_bounds__(256, 2) void att_write(const unsigned char* __restrict__ vT8,
                                                    const float* __restrict__ S,
                                                    float* __restrict__ att)
{
    __shared__ float tile[64][260];       // block-shared 64 x 256 staging (+pad)
    __shared__ float inv_lds[64];

    int bid = blockIdx.x;
    int b = bid & 7;                       // batch pinned to XCD
    int rowblock = bid >> 3;
    int rowbase = rowblock * 64;
    int rot = rowblock & 15;               // jt phase rotation (kept from R14)

    int w    = threadIdx.x >> 6;           // wave id: column window within tile
    int lane = threadIdx.x & 63;
    int r16  = lane & 15;
    int kg   = lane >> 4;

    const unsigned char* base = vT8 + (size_t)b * N_ * C_;

    // A fragments: rows rowbase..rowbase+63, full K=128. 16 x long = 32 VGPR.
    long a8[4][4];
    #pragma unroll
    for (int mi = 0; mi < 4; ++mi)
        #pragma unroll
        for (int ks = 0; ks < 4; ++ks)
            a8[mi][ks] = *reinterpret_cast<const long*>(
                base + (size_t)(rowbase + mi * 16 + r16) * C_ + ks * 32 + kg * 8);

    // inv_i = 1/(N + v_i.S): first-order denominator (validated R4+).
    const float* Sb = S + b * C_;
    #pragma unroll
    for (int mi = 0; mi < 4; ++mi) {
        float d = 0.f;
        #pragma unroll
        for (int ks = 0; ks < 4; ++ks) {
            int k0 = ks * 32 + kg * 8;
            unsigned lo = (unsigned)(a8[mi][ks] & 0xffffffffu);
            unsigned hi = (unsigned)(((unsigned long)a8[mi][ks]) >> 32);
            #pragma unroll
            for (int j = 0; j < 4; ++j) d += fp8tof(lo, j) * Sb[k0 + j];
            #pragma unroll
            for (int j = 0; j < 4; ++j) d += fp8tof(hi, j) * Sb[k0 + 4 + j];
        }
        d += __shfl_xor(d, 16, 64);
        d += __shfl_xor(d, 32, 64);
        if (threadIdx.x < 16) inv_lds[mi * 16 + r16] = 1.0f / ((float)N_ + d);
    }
    __syncthreads();   // prologue only — full sync is fine here

    // per-thread iv for the acc elements it stages: row = mi*16 + kg*4 + r
    float iv_acc[4][4];
    #pragma unroll
    for (int mi = 0; mi < 4; ++mi)
        #pragma unroll
        for (int r = 0; r < 4; ++r)
            iv_acc[mi][r] = inv_lds[mi * 16 + kg * 4 + r];

    float* ab = att + (size_t)b * N_ * N_;

    // prologue: B-frags for first (rotated) tile
    long bb8[4][4];
    #pragma unroll
    for (int ks = 0; ks < 4; ++ks)
        #pragma unroll
        for (int nj = 0; nj < 4; ++nj)
            bb8[ks][nj] = *reinterpret_cast<const long*>(
                base + (size_t)(rot * 256 + w * 64 + nj * 16 + r16) * C_ + ks * 32 + kg * 8);

    #pragma unroll 1
    for (int jt0 = 0; jt0 < 16; ++jt0) {
        int jt = (jt0 + rot) & 15;

        f32x4 acc[4][4] = {};
        #pragma unroll
        for (int ks = 0; ks < 4; ++ks)
            #pragma unroll
            for (int mi = 0; mi < 4; ++mi)
                #pragma unroll
                for (int nj = 0; nj < 4; ++nj)
                    acc[mi][nj] = __builtin_amdgcn_mfma_f32_16x16x32_fp8_fp8(
                        a8[mi][ks], bb8[ks][nj], acc[mi][nj], 0, 0, 0);

        // prefetch next tile's B-frags (WAR reuse) BEFORE the stores.
        if (jt0 < 15) {
            int pf = (((jt0 + 1 + rot) & 15) * 256) + w * 64;
            #pragma unroll
            for (int ks = 0; ks < 4; ++ks)
                #pragma unroll
                for (int nj = 0; nj < 4; ++nj)
                    bb8[ks][nj] = *reinterpret_cast<const long*>(
                        base + (size_t)(pf + nj * 16 + r16) * C_ + ks * 32 + kg * 8);
        }

        // finish softmax IN REGISTERS (exp overlaps prefetch latency), then
        // stage FINAL values into the block tile.
        #pragma unroll
        for (int mi = 0; mi < 4; ++mi)
            #pragma unroll
            for (int nj = 0; nj < 4; ++nj)
                #pragma unroll
                for (int r = 0; r < 4; ++r)
                    tile[mi * 16 + kg * 4 + r][w * 64 + nj * 16 + r16] =
                        __expf(acc[mi][nj][r]) * iv_acc[mi][r];

        lds_barrier();   // LDS-order only: no vmcnt drain of stores/prefetch

        // store phase: wave w owns rows w*16..w*16+15; one instruction per row
        // = 64 lanes x 16 B = 1 KB fully contiguous. Pure ds_read -> NT store.
        #pragma unroll
        for (int p = 0; p < 16; ++p) {
            int row = w * 16 + p;
            f32x4 o = *reinterpret_cast<const f32x4*>(&tile[row][lane * 4]);
            __builtin_nontemporal_store(o,
                reinterpret_cast<f32x4*>(&ab[(size_t)(rowbase + row) * N_ + jt * 256 + lane * 4]));
        }

        lds_barrier();   // reads done -> tile reusable next jt (LDS-order only)
    }
}

// ---------------------------------------------------------------------------
// K4: out = gamma * (V @ attention^T) + xs. EXACT R13-R19 version.
// ---------------------------------------------------------------------------
__global__ __launch_bounds__(256) void pv_update(const float* __restrict__ gamma,
                                                 const unsigned char* __restrict__ vT8,
                                                 const float* __restrict__ att,
                                                 float* __restrict__ out)
{
    float g = gamma[0];
    if (g == 0.0f) return;

    int b  = blockIdx.y;
    int n0 = blockIdx.x * 128 + (threadIdx.x >> 7) * 64;
    int c  = threadIdx.x & 127;

    const unsigned char* vb = vT8 + (size_t)b * N_ * C_;

    for (int i = 0; i < 64; ++i) {
        int n = n0 + i;
        const float* arow = att + ((size_t)b * N_ + n) * N_;
        float acc = 0.f;
        for (int m = 0; m < N_; ++m)
            acc += __builtin_amdgcn_cvt_f32_fp8((unsigned)vb[(size_t)m * C_ + c], 0) * arow[m];
        size_t oi = ((size_t)b * C_ + c) * N_ + n;
        out[oi] = g * acc + out[oi];
    }
}

// ---------------------------------------------------------------------------
extern "C" void kernel_launch(void* const* d_in, const int* in_sizes, int n_in,
                              void* d_out, int out_size, void* d_ws, size_t ws_size,
                              hipStream_t stream)
{
    const float* x     = (const float*)d_in[0];
    const float* gamma = (const float*)d_in[1];

    float* out = (float*)d_out;                        // [B][C][N]  (4,194,304 f32)
    float* att = out + (size_t)B_ * C_ * N_;           // [B][N][N]  (134,217,728 f32)
    unsigned char* vT8 = (unsigned char*)d_ws;         // [B][N][C]  fp8, 4 MB
    float* S   = (float*)(vT8 + (size_t)B_ * N_ * C_); // [B][C] f32, 4 KB

    chan_softmax<<<256, 128, 0, stream>>>(x, out, vT8, S);
    colsum<<<256, 256, 0, stream>>>(vT8, S);
    att_write<<<(N_ / 64) * B_, 256, 0, stream>>>(vT8, S, att);
    pv_update<<<dim3(32, B_), 256, 0, stream>>>(gamma, vT8, att, out);
}